// Round 6
// baseline (41557.797 us; speedup 1.0000x reference)
//
#include <hip/hip_runtime.h>
#include <hip/hip_fp16.h>
#include <math.h>

// Problem dims
#define T_STEPS 1024
#define BATCH   128
#define D_IN    256
#define H_DIM   256
#define NCOL    1024  // 4 gates * H
#define CH      16    // x-precompute chunk (steps)
#define NRES    12    // register-resident WH m-groups per column (k = 0..95)

typedef _Float16 half2_t __attribute__((ext_vector_type(2)));

__device__ __forceinline__ float sigmoidf_(float x) {
    return 1.0f / (1.0f + __expf(-x));
}

__device__ __forceinline__ float tanhf_(float x) {
    float ax = fabsf(x);
    float t = __expf(-2.0f * ax);
    float r = (1.0f - t) / (1.0f + t);
    return copysignf(r, x);
}

// 2-way f16 dot with f32 accumulate: acc += w.x*h.x + w.y*h.y
__device__ __forceinline__ float dot2f(unsigned int w, unsigned int h, float acc) {
#if __has_builtin(__builtin_amdgcn_fdot2)
    return __builtin_amdgcn_fdot2(__builtin_bit_cast(half2_t, w),
                                  __builtin_bit_cast(half2_t, h), acc, false);
#else
    __half2 wv = *(__half2*)&w, hv = *(__half2*)&h;
    acc = fmaf(__half2float(wv.x), __half2float(hv.x), acc);
    return fmaf(__half2float(wv.y), __half2float(hv.y), acc);
#endif
}

// one k-octet: 4 hi-dot2 + 4 lo-dot2 against weight uint4
__device__ __forceinline__ void dot8(uint4 wv, uint4 hv, uint4 lv,
                                     float& aH, float& aL) {
    aH = dot2f(wv.x, hv.x, aH); aH = dot2f(wv.y, hv.y, aH);
    aH = dot2f(wv.z, hv.z, aH); aH = dot2f(wv.w, hv.w, aH);
    aL = dot2f(wv.x, lv.x, aL); aL = dot2f(wv.y, lv.y, aL);
    aL = dot2f(wv.z, lv.z, aL); aL = dot2f(wv.w, lv.w, aL);
}

__device__ __forceinline__ unsigned int packh2(float a, float b) {
    __half2 p = __floats2half2_rn(a, b);
    return *(unsigned int*)&p;
}

__device__ __forceinline__ uint4 pack8(const float* p) {
    return make_uint4(packh2(p[0], p[1]), packh2(p[2], p[3]),
                      packh2(p[4], p[5]), packh2(p[6], p[7]));
}

// Layouts (j = gate*256 + h, m = 0..31 indexes k-octets):
//   WX4[m*1024 + j] = uint4 of f16 W[j][8m..8m+7]         (x part)
//   WH4[m*1024 + j] = uint4 of f16 W[j][256+8m..256+8m+7]  (hx part)
//   biasc[1024] fp32
__global__ __launch_bounds__(256) void prep_kernel(
    const float* __restrict__ Wf, const float* __restrict__ Wi,
    const float* __restrict__ Wg, const float* __restrict__ Wo,
    const float* __restrict__ bf, const float* __restrict__ bi,
    const float* __restrict__ bg, const float* __restrict__ bo,
    uint4* __restrict__ WX4, uint4* __restrict__ WH4,
    float* __restrict__ biasc)
{
    int idx = blockIdx.x * 256 + threadIdx.x;   // 0 .. 32767
    int m = idx >> 10;
    int j = idx & 1023;
    int g = j >> 8;
    int h = j & 255;
    const float* W = (g == 0) ? Wf : (g == 1) ? Wi : (g == 2) ? Wg : Wo;
    const float* row = W + h * (D_IN + H_DIM);
    WX4[idx] = pack8(row + 8 * m);
    WH4[idx] = pack8(row + D_IN + 8 * m);
    if (idx < NCOL) {
        const float* bb = (g == 0) ? bf : (g == 1) ? bi : (g == 2) ? bg : bo;
        biasc[idx] = bb[h];
    }
}

// One block per batch row; 512 threads (8 waves, 2 waves/EU -> VGPR cap 256).
// Thread tid owns columns j0 = tid (gates f,i) and j1 = tid+512 (gates g,o).
//  - chunk phase every CH steps: x-part preactivations in registers (f32 FMA,
//    wave-uniform x loads), bit-identical to the proven r4 path.
//  - steady step: 12/32 WH m-groups per column register-resident; remaining 20
//    streamed via two 4-deep double buffers refilled ahead of use; next-step
//    refill issued during the est/update phases (weights are step-invariant).
//  - est layer 1 over all 8 waves (4 units each); layers 2-3 redundant
//    per-thread on waves 0-3; 3 barriers/step.
__global__ __launch_bounds__(512)
__attribute__((amdgpu_waves_per_eu(2, 2)))
void qlstm_kernel(
    const float* __restrict__ x,
    const uint4* __restrict__ WX4,
    const uint4* __restrict__ WH4,
    const float* __restrict__ biasc,
    const float* __restrict__ estW1, const float* __restrict__ estb1,
    const float* __restrict__ estW2, const float* __restrict__ estb2,
    const float* __restrict__ estW3, const float* __restrict__ estb3,
    float* __restrict__ out)
{
    __shared__ __align__(16) __half hxh[H_DIM];   // hi(hx)
    __shared__ __align__(16) __half hxl[H_DIM];   // lo(hx)
    __shared__ __align__(16) float gact[NCOL];    // activated gates
    __shared__ float w1[4 * 8 * H_DIM];  // estW1 permuted: [u][q*64+l] = h=4l+q
    __shared__ float sb1[32];
    __shared__ float sW2[128];
    __shared__ float sb2[16];
    __shared__ float sW3[16];
    __shared__ float sb3[4];
    __shared__ float sh1[32];            // est layer-1 outputs [gate*8+j]

    const int b    = blockIdx.x;
    const int tid  = threadIdx.x;
    const int w    = tid >> 6;
    const int lane = tid & 63;

    // stage est params; permute w1 so lane-l float4 reads of gact are stride-1
    for (int i = tid; i < 4 * 8 * H_DIM; i += 512) {
        int p = i & 255;
        int base = i & ~255;
        int h = 4 * (p & 63) + (p >> 6);
        w1[i] = estW1[base + h];
    }
    if (tid < 32)  sb1[tid] = estb1[tid];
    if (tid < 128) sW2[tid] = estW2[tid];
    if (tid < 16)  { sb2[tid] = estb2[tid]; sW3[tid] = estW3[tid]; }
    if (tid < 4)   sb3[tid] = estb3[tid];
    if (tid < H_DIM) {
        hxh[tid] = __float2half(0.0f);
        hxl[tid] = __float2half(0.0f);
    }
    float c_reg = 0.0f, h_reg = 0.0f;
    const float bj0 = biasc[tid];
    const float bj1 = biasc[tid + 512];
    __syncthreads();

    const uint4* hh = (const uint4*)hxh;   // 32 x (8 halves): k = 8m..8m+7
    const uint4* hl = (const uint4*)hxl;
    const uint4* wc0 = WH4 + tid;
    const uint4* wc1 = WH4 + tid + 512;

    // register-resident low k-groups (never re-fetched): m = 0..NRES-1
    uint4 wp0[NRES], wp1[NRES];
    #pragma unroll
    for (int m = 0; m < NRES; m++) { wp0[m] = wc0[m << 10]; wp1[m] = wc1[m << 10]; }

    float pa0[CH], pa1[CH];
    uint4 bA0[4], bA1[4], bB0[4], bB1[4];

    for (int t0 = 0; t0 < T_STEPS; t0 += CH) {
        // ---- chunk phase: pa[s] = bias + Wx . x[t0+s], pure registers ----
        #pragma unroll
        for (int s = 0; s < CH; s++) { pa0[s] = bj0; pa1[s] = bj1; }
        {
            const float* xb = x + ((size_t)t0 * BATCH + b) * D_IN;
            for (int m = 0; m < 32; m++) {
                uint4 wv0 = WX4[(m << 10) + tid];
                uint4 wv1 = WX4[(m << 10) + tid + 512];
                __half2 p0 = *(__half2*)&wv0.x, p1 = *(__half2*)&wv0.y;
                __half2 p2 = *(__half2*)&wv0.z, p3 = *(__half2*)&wv0.w;
                __half2 q0 = *(__half2*)&wv1.x, q1 = *(__half2*)&wv1.y;
                __half2 q2 = *(__half2*)&wv1.z, q3 = *(__half2*)&wv1.w;
                float u0 = __half2float(p0.x), u1 = __half2float(p0.y);
                float u2 = __half2float(p1.x), u3 = __half2float(p1.y);
                float u4 = __half2float(p2.x), u5 = __half2float(p2.y);
                float u6 = __half2float(p3.x), u7 = __half2float(p3.y);
                float v0 = __half2float(q0.x), v1 = __half2float(q0.y);
                float v2 = __half2float(q1.x), v3 = __half2float(q1.y);
                float v4 = __half2float(q2.x), v5 = __half2float(q2.y);
                float v6 = __half2float(q3.x), v7 = __half2float(q3.y);
                #pragma unroll
                for (int s = 0; s < CH; s++) {
                    // wave-uniform f32 reads of this row's x octet (scalarized)
                    const float* xr = xb + (size_t)s * (BATCH * D_IN) + (m << 3);
                    float4 xa = *(const float4*)xr;
                    float4 xc = *(const float4*)(xr + 4);
                    float a = pa0[s];
                    a = fmaf(u0, xa.x, a); a = fmaf(u1, xa.y, a);
                    a = fmaf(u2, xa.z, a); a = fmaf(u3, xa.w, a);
                    a = fmaf(u4, xc.x, a); a = fmaf(u5, xc.y, a);
                    a = fmaf(u6, xc.z, a); a = fmaf(u7, xc.w, a);
                    pa0[s] = a;
                    float c = pa1[s];
                    c = fmaf(v0, xa.x, c); c = fmaf(v1, xa.y, c);
                    c = fmaf(v2, xa.z, c); c = fmaf(v3, xa.w, c);
                    c = fmaf(v4, xc.x, c); c = fmaf(v5, xc.y, c);
                    c = fmaf(v6, xc.z, c); c = fmaf(v7, xc.w, c);
                    pa1[s] = c;
                }
            }
        }
        // prefetch first streamed group for step 0 of this chunk: m = 12..15
        #pragma unroll
        for (int i = 0; i < 4; i++) {
            bA0[i] = wc0[(NRES + i) << 10];
            bA1[i] = wc1[(NRES + i) << 10];
        }

        // ---- CH recurrent steps consuming pa ----
        #pragma unroll 1
        for (int s = 0; s < CH; s++) {
            const int t = t0 + s;
            float aH0 = pa0[0], aL0 = 0.0f, aH1 = pa1[0], aL1 = 0.0f;
            #pragma unroll
            for (int i = 0; i < CH - 1; i++) { pa0[i] = pa0[i + 1]; pa1[i] = pa1[i + 1]; }

            // issue bB <- m16..19 early
            #pragma unroll
            for (int i = 0; i < 4; i++) {
                bB0[i] = wc0[(16 + i) << 10];
                bB1[i] = wc1[(16 + i) << 10];
            }

            // resident groups m = 0..11 (h slices shared by both columns)
            #pragma unroll
            for (int m = 0; m < NRES; m++) {
                uint4 hv = hh[m], lv = hl[m];
                dot8(wp0[m], hv, lv, aH0, aL0);
                dot8(wp1[m], hv, lv, aH1, aL1);
            }
            // bA: m12..15 ; refill bA <- m20..23
            #pragma unroll
            for (int i = 0; i < 4; i++) {
                uint4 hv = hh[12 + i], lv = hl[12 + i];
                dot8(bA0[i], hv, lv, aH0, aL0);
                dot8(bA1[i], hv, lv, aH1, aL1);
            }
            #pragma unroll
            for (int i = 0; i < 4; i++) {
                bA0[i] = wc0[(20 + i) << 10];
                bA1[i] = wc1[(20 + i) << 10];
            }
            // bB: m16..19 ; refill bB <- m24..27
            #pragma unroll
            for (int i = 0; i < 4; i++) {
                uint4 hv = hh[16 + i], lv = hl[16 + i];
                dot8(bB0[i], hv, lv, aH0, aL0);
                dot8(bB1[i], hv, lv, aH1, aL1);
            }
            #pragma unroll
            for (int i = 0; i < 4; i++) {
                bB0[i] = wc0[(24 + i) << 10];
                bB1[i] = wc1[(24 + i) << 10];
            }
            // bA: m20..23 ; refill bA <- m28..31
            #pragma unroll
            for (int i = 0; i < 4; i++) {
                uint4 hv = hh[20 + i], lv = hl[20 + i];
                dot8(bA0[i], hv, lv, aH0, aL0);
                dot8(bA1[i], hv, lv, aH1, aL1);
            }
            #pragma unroll
            for (int i = 0; i < 4; i++) {
                bA0[i] = wc0[(28 + i) << 10];
                bA1[i] = wc1[(28 + i) << 10];
            }
            // bB: m24..27
            #pragma unroll
            for (int i = 0; i < 4; i++) {
                uint4 hv = hh[24 + i], lv = hl[24 + i];
                dot8(bB0[i], hv, lv, aH0, aL0);
                dot8(bB1[i], hv, lv, aH1, aL1);
            }
            // bA: m28..31
            #pragma unroll
            for (int i = 0; i < 4; i++) {
                uint4 hv = hh[28 + i], lv = hl[28 + i];
                dot8(bA0[i], hv, lv, aH0, aL0);
                dot8(bA1[i], hv, lv, aH1, aL1);
            }

            float acc0 = aH0 + aL0;
            float acc1 = aH1 + aL1;

            // col j0 (gates f,i): sigmoid. col j1: gate g (tid<256) tanh else o sigmoid
            float v0a = sigmoidf_(acc0);
            float v1a = (tid < 256) ? tanhf_(acc1) : sigmoidf_(acc1);
            gact[tid] = v0a;
            gact[tid + 512] = v1a;
            __syncthreads();   // A: gates visible

            // est layer 1: 32 (gate,j) units over 8 waves, 4 per wave
            {
                const int ge = w >> 1;
                float4 gv = ((const float4*)(gact + (ge << 8)))[lane];
                #pragma unroll
                for (int uu = 0; uu < 4; uu++) {
                    const int u = ge * 8 + (w & 1) * 4 + uu;
                    const float* wr = &w1[u * H_DIM];
                    float s1 = fmaf(gv.x, wr[lane],
                               fmaf(gv.y, wr[lane + 64],
                               fmaf(gv.z, wr[lane + 128], gv.w * wr[lane + 192])));
                    #pragma unroll
                    for (int m2 = 1; m2 < 64; m2 <<= 1) s1 += __shfl_xor(s1, m2, 64);
                    if (lane == 0) sh1[u] = tanhf_(s1 + sb1[u]);
                }
            }
            __syncthreads();   // E: sh1 visible

            // prefetch next step's bA (m12..15) across the update phase
            if (s + 1 < CH) {
                #pragma unroll
                for (int i = 0; i < 4; i++) {
                    bA0[i] = wc0[(NRES + i) << 10];
                    bA1[i] = wc1[(NRES + i) << 10];
                }
            }

            // est layers 2-3 (redundant per-thread) + state update: waves 0-3
            if (tid < 256) {
                float esc[4];
                #pragma unroll
                for (int g = 0; g < 4; g++) {
                    float h2[4];
                    #pragma unroll
                    for (int j = 0; j < 4; j++) {
                        float s2 = sb2[g * 4 + j];
                        #pragma unroll
                        for (int q = 0; q < 8; q++)
                            s2 = fmaf(sh1[g * 8 + q], sW2[g * 32 + j * 8 + q], s2);
                        h2[j] = tanhf_(s2);
                    }
                    float s3 = sb3[g];
                    #pragma unroll
                    for (int q = 0; q < 4; q++) s3 = fmaf(h2[q], sW3[g * 4 + q], s3);
                    esc[g] = sigmoidf_(s3);
                }
                float f  = gact[tid]       * esc[0];
                float ii = gact[256 + tid] * esc[1];
                float gg = gact[512 + tid] * esc[2];
                float o  = gact[768 + tid] * esc[3];
                c_reg = fmaf(f, c_reg, ii * gg);
                h_reg = o * tanhf_(c_reg);
                __half hi = __float2half_rn(h_reg);
                hxh[tid] = hi;
                hxl[tid] = __float2half_rn(h_reg - __half2float(hi));
                out[((size_t)t * BATCH + b) * H_DIM + tid] = h_reg;
            }
            __syncthreads();   // C: new hx visible to all waves
        }
    }

    if (tid < 256) {
        const size_t stacked = (size_t)T_STEPS * BATCH * H_DIM;
        out[stacked + (size_t)b * H_DIM + tid] = h_reg;
        out[stacked + (size_t)BATCH * H_DIM + (size_t)b * H_DIM + tid] = c_reg;
    }
}

extern "C" void kernel_launch(void* const* d_in, const int* in_sizes, int n_in,
                              void* d_out, int out_size, void* d_ws, size_t ws_size,
                              hipStream_t stream) {
    const float* x     = (const float*)d_in[0];
    const float* Wf    = (const float*)d_in[1];
    const float* bf    = (const float*)d_in[2];
    const float* Wi    = (const float*)d_in[3];
    const float* bi    = (const float*)d_in[4];
    const float* Wg    = (const float*)d_in[5];
    const float* bg    = (const float*)d_in[6];
    const float* Wo    = (const float*)d_in[7];
    const float* bo    = (const float*)d_in[8];
    const float* estW1 = (const float*)d_in[9];
    const float* estb1 = (const float*)d_in[10];
    const float* estW2 = (const float*)d_in[11];
    const float* estb2 = (const float*)d_in[12];
    const float* estW3 = (const float*)d_in[13];
    const float* estb3 = (const float*)d_in[14];

    uint4* WX4   = (uint4*)d_ws;                 // 32768 uint4 = 512 KB
    uint4* WH4   = WX4 + 32768;                  // 512 KB
    float* biasc = (float*)(WH4 + 32768);        // 4 KB

    prep_kernel<<<128, 256, 0, stream>>>(Wf, Wi, Wg, Wo, bf, bi, bg, bo,
                                         WX4, WH4, biasc);
    qlstm_kernel<<<BATCH, 512, 0, stream>>>(
        x, WX4, WH4, biasc,
        estW1, estb1, estW2, estb2, estW3, estb3, (float*)d_out);
}

// Round 7
// 35995.413 us; speedup vs baseline: 1.1545x; 1.1545x over previous
//
#include <hip/hip_runtime.h>
#include <hip/hip_fp16.h>
#include <math.h>

// Problem dims
#define T_STEPS 1024
#define BATCH   128
#define D_IN    256
#define H_DIM   256
#define NCOL    1024  // 4 gates * H
#define CH      16    // x-precompute chunk (steps)

typedef _Float16 half2_t __attribute__((ext_vector_type(2)));

__device__ __forceinline__ float sigmoidf_(float x) {
    return 1.0f / (1.0f + __expf(-x));
}

__device__ __forceinline__ float tanhf_(float x) {
    float ax = fabsf(x);
    float t = __expf(-2.0f * ax);
    float r = (1.0f - t) / (1.0f + t);
    return copysignf(r, x);
}

// 2-way f16 dot with f32 accumulate: acc += w.x*h.x + w.y*h.y
__device__ __forceinline__ float dot2f(unsigned int w, unsigned int h, float acc) {
#if __has_builtin(__builtin_amdgcn_fdot2)
    return __builtin_amdgcn_fdot2(__builtin_bit_cast(half2_t, w),
                                  __builtin_bit_cast(half2_t, h), acc, false);
#else
    __half2 wv = *(__half2*)&w, hv = *(__half2*)&h;
    acc = fmaf(__half2float(wv.x), __half2float(hv.x), acc);
    return fmaf(__half2float(wv.y), __half2float(hv.y), acc);
#endif
}

// one k-octet: 4 hi-dot2 + 4 lo-dot2 against weight uint4
__device__ __forceinline__ void dot8(uint4 wv, uint4 hv, uint4 lv,
                                     float& aH, float& aL) {
    aH = dot2f(wv.x, hv.x, aH); aH = dot2f(wv.y, hv.y, aH);
    aH = dot2f(wv.z, hv.z, aH); aH = dot2f(wv.w, hv.w, aH);
    aL = dot2f(wv.x, lv.x, aL); aL = dot2f(wv.y, lv.y, aL);
    aL = dot2f(wv.z, lv.z, aL); aL = dot2f(wv.w, lv.w, aL);
}

__device__ __forceinline__ unsigned int packh2(float a, float b) {
    __half2 p = __floats2half2_rn(a, b);
    return *(unsigned int*)&p;
}

__device__ __forceinline__ uint4 pack8(const float* p) {
    return make_uint4(packh2(p[0], p[1]), packh2(p[2], p[3]),
                      packh2(p[4], p[5]), packh2(p[6], p[7]));
}

// Layouts (j = gate*256 + h, m = 0..31 indexes k-octets):
//   WX4[m*1024 + j] = uint4 of f16 W[j][8m..8m+7]         (x part)
//   WH4[m*1024 + j] = uint4 of f16 W[j][256+8m..256+8m+7]  (hx part)
//   biasc[1024] fp32
__global__ __launch_bounds__(256) void prep_kernel(
    const float* __restrict__ Wf, const float* __restrict__ Wi,
    const float* __restrict__ Wg, const float* __restrict__ Wo,
    const float* __restrict__ bf, const float* __restrict__ bi,
    const float* __restrict__ bg, const float* __restrict__ bo,
    uint4* __restrict__ WX4, uint4* __restrict__ WH4,
    float* __restrict__ biasc)
{
    int idx = blockIdx.x * 256 + threadIdx.x;   // 0 .. 32767
    int m = idx >> 10;
    int j = idx & 1023;
    int g = j >> 8;
    int h = j & 255;
    const float* W = (g == 0) ? Wf : (g == 1) ? Wi : (g == 2) ? Wg : Wo;
    const float* row = W + h * (D_IN + H_DIM);
    WX4[idx] = pack8(row + 8 * m);
    WH4[idx] = pack8(row + D_IN + 8 * m);
    if (idx < NCOL) {
        const float* bb = (g == 0) ? bf : (g == 1) ? bi : (g == 2) ? bg : bo;
        biasc[idx] = bb[h];
    }
}

// One block per batch row; 512 threads (8 waves, 2/EU, 1 block/CU, VGPR cap 128).
// Thread tid owns columns j0 = tid (gates f,i) and j1 = tid+512 (gates g,o).
//  - chunk phase every CH steps: x-part preactivations in registers (f32 FMA,
//    wave-uniform x loads), then dumped to LDS (frees 32 regs for steady loop).
//  - steady step: all 32 WH m-groups streamed from L2 through a 2-deep,
//    4-group double buffer; each group issued one use-block ahead (weight
//    addresses never depend on h, so the pipeline never blocks on recurrence).
//  - per-CU LDS h-broadcasts halved vs the 1024-thread layout (8 waves x 64).
//  - est layer 1 over all 8 waves (4 units each); layers 2-3 redundant
//    per-thread on waves 0-3; 3 barriers/step.
__global__ __launch_bounds__(512)
__attribute__((amdgpu_waves_per_eu(2, 2)))
void qlstm_kernel(
    const float* __restrict__ x,
    const uint4* __restrict__ WX4,
    const uint4* __restrict__ WH4,
    const float* __restrict__ biasc,
    const float* __restrict__ estW1, const float* __restrict__ estb1,
    const float* __restrict__ estW2, const float* __restrict__ estb2,
    const float* __restrict__ estW3, const float* __restrict__ estb3,
    float* __restrict__ out)
{
    __shared__ __align__(16) __half hxh[H_DIM];   // hi(hx)
    __shared__ __align__(16) __half hxl[H_DIM];   // lo(hx)
    __shared__ __align__(16) float gact[NCOL];    // activated gates
    __shared__ float w1[4 * 8 * H_DIM];  // estW1 permuted: [u][q*64+l] = h=4l+q
    __shared__ float sb1[32];
    __shared__ float sW2[128];
    __shared__ float sb2[16];
    __shared__ float sW3[16];
    __shared__ float sb3[4];
    __shared__ float sh1[32];            // est layer-1 outputs [gate*8+j]
    __shared__ float palds[2 * CH * 512];  // chunk preacts [col][s][tid]

    const int b    = blockIdx.x;
    const int tid  = threadIdx.x;
    const int w    = tid >> 6;
    const int lane = tid & 63;

    // stage est params; permute w1 so lane-l float4 reads of gact are stride-1
    for (int i = tid; i < 4 * 8 * H_DIM; i += 512) {
        int p = i & 255;
        int base = i & ~255;
        int h = 4 * (p & 63) + (p >> 6);
        w1[i] = estW1[base + h];
    }
    if (tid < 32)  sb1[tid] = estb1[tid];
    if (tid < 128) sW2[tid] = estW2[tid];
    if (tid < 16)  { sb2[tid] = estb2[tid]; sW3[tid] = estW3[tid]; }
    if (tid < 4)   sb3[tid] = estb3[tid];
    if (tid < H_DIM) {
        hxh[tid] = __float2half(0.0f);
        hxl[tid] = __float2half(0.0f);
    }
    float c_reg = 0.0f, h_reg = 0.0f;
    const float bj0 = biasc[tid];
    const float bj1 = biasc[tid + 512];
    __syncthreads();

    const uint4* hh = (const uint4*)hxh;   // 32 x (8 halves): k = 8m..8m+7
    const uint4* hl = (const uint4*)hxl;
    const uint4* wc0 = WH4 + tid;
    const uint4* wc1 = WH4 + tid + 512;
    const uint4* wx0 = WX4 + tid;
    const uint4* wx1 = WX4 + tid + 512;

    uint4 bA0[4], bA1[4], bB0[4], bB1[4];

    // prime the steady-state pipeline: group m0..3 (refreshed at each step end)
    #pragma unroll
    for (int i = 0; i < 4; i++) { bA0[i] = wc0[i << 10]; bA1[i] = wc1[i << 10]; }

    for (int t0 = 0; t0 < T_STEPS; t0 += CH) {
        // ---- chunk phase: pa[s] = bias + Wx . x[t0+s] in regs, dump to LDS ----
        {
            float pa0[CH], pa1[CH];
            #pragma unroll
            for (int s = 0; s < CH; s++) { pa0[s] = bj0; pa1[s] = bj1; }
            const float* xb = x + ((size_t)t0 * BATCH + b) * D_IN;
            for (int m = 0; m < 32; m++) {
                uint4 wv0 = wx0[m << 10];
                uint4 wv1 = wx1[m << 10];
                __half2 p0 = *(__half2*)&wv0.x, p1 = *(__half2*)&wv0.y;
                __half2 p2 = *(__half2*)&wv0.z, p3 = *(__half2*)&wv0.w;
                __half2 q0 = *(__half2*)&wv1.x, q1 = *(__half2*)&wv1.y;
                __half2 q2 = *(__half2*)&wv1.z, q3 = *(__half2*)&wv1.w;
                float u0 = __half2float(p0.x), u1 = __half2float(p0.y);
                float u2 = __half2float(p1.x), u3 = __half2float(p1.y);
                float u4 = __half2float(p2.x), u5 = __half2float(p2.y);
                float u6 = __half2float(p3.x), u7 = __half2float(p3.y);
                float v0 = __half2float(q0.x), v1 = __half2float(q0.y);
                float v2 = __half2float(q1.x), v3 = __half2float(q1.y);
                float v4 = __half2float(q2.x), v5 = __half2float(q2.y);
                float v6 = __half2float(q3.x), v7 = __half2float(q3.y);
                #pragma unroll
                for (int s = 0; s < CH; s++) {
                    // wave-uniform f32 reads of this row's x octet
                    const float* xr = xb + (size_t)s * (BATCH * D_IN) + (m << 3);
                    float4 xa = *(const float4*)xr;
                    float4 xc = *(const float4*)(xr + 4);
                    float a = pa0[s];
                    a = fmaf(u0, xa.x, a); a = fmaf(u1, xa.y, a);
                    a = fmaf(u2, xa.z, a); a = fmaf(u3, xa.w, a);
                    a = fmaf(u4, xc.x, a); a = fmaf(u5, xc.y, a);
                    a = fmaf(u6, xc.z, a); a = fmaf(u7, xc.w, a);
                    pa0[s] = a;
                    float c = pa1[s];
                    c = fmaf(v0, xa.x, c); c = fmaf(v1, xa.y, c);
                    c = fmaf(v2, xa.z, c); c = fmaf(v3, xa.w, c);
                    c = fmaf(v4, xc.x, c); c = fmaf(v5, xc.y, c);
                    c = fmaf(v6, xc.z, c); c = fmaf(v7, xc.w, c);
                    pa1[s] = c;
                }
            }
            // dump (own-thread slots; read back per step with runtime s)
            #pragma unroll
            for (int s = 0; s < CH; s++) {
                palds[s * 512 + tid] = pa0[s];
                palds[CH * 512 + s * 512 + tid] = pa1[s];
            }
        }

        // ---- CH recurrent steps ----
        #pragma unroll 1
        for (int s = 0; s < CH; s++) {
            const int t = t0 + s;
            float aH0 = palds[s * 512 + tid],            aL0 = 0.0f;
            float aH1 = palds[CH * 512 + s * 512 + tid], aL1 = 0.0f;

            // 8 groups of 4 m; double-buffered, each group issued 1 block ahead
            #define GRP_ISSUE(B0, B1, MB)                                     \
                _Pragma("unroll") for (int i = 0; i < 4; i++) {               \
                    B0[i] = wc0[(MB + i) << 10];                              \
                    B1[i] = wc1[(MB + i) << 10];                              \
                }
            #define GRP_USE(B0, B1, MB)                                       \
                _Pragma("unroll") for (int i = 0; i < 4; i++) {               \
                    uint4 hv = hh[MB + i], lv = hl[MB + i];                   \
                    dot8(B0[i], hv, lv, aH0, aL0);                            \
                    dot8(B1[i], hv, lv, aH1, aL1);                            \
                }
            GRP_ISSUE(bB0, bB1, 4)   GRP_USE(bA0, bA1, 0)
            GRP_ISSUE(bA0, bA1, 8)   GRP_USE(bB0, bB1, 4)
            GRP_ISSUE(bB0, bB1, 12)  GRP_USE(bA0, bA1, 8)
            GRP_ISSUE(bA0, bA1, 16)  GRP_USE(bB0, bB1, 12)
            GRP_ISSUE(bB0, bB1, 20)  GRP_USE(bA0, bA1, 16)
            GRP_ISSUE(bA0, bA1, 24)  GRP_USE(bB0, bB1, 20)
            GRP_ISSUE(bB0, bB1, 28)  GRP_USE(bA0, bA1, 24)
            GRP_USE(bB0, bB1, 28)    GRP_ISSUE(bA0, bA1, 0)  // next step
            #undef GRP_ISSUE
            #undef GRP_USE

            float acc0 = aH0 + aL0;
            float acc1 = aH1 + aL1;

            // col j0 (gates f,i): sigmoid. col j1: gate g (tid<256) tanh else o
            float v0a = sigmoidf_(acc0);
            float v1a = (tid < 256) ? tanhf_(acc1) : sigmoidf_(acc1);
            gact[tid] = v0a;
            gact[tid + 512] = v1a;
            __syncthreads();   // A: gates visible

            // est layer 1: 32 (gate,j) units over 8 waves, 4 per wave
            {
                const int ge = w >> 1;
                float4 gv = ((const float4*)(gact + (ge << 8)))[lane];
                #pragma unroll
                for (int uu = 0; uu < 4; uu++) {
                    const int u = ge * 8 + (w & 1) * 4 + uu;
                    const float* wr = &w1[u * H_DIM];
                    float s1 = fmaf(gv.x, wr[lane],
                               fmaf(gv.y, wr[lane + 64],
                               fmaf(gv.z, wr[lane + 128], gv.w * wr[lane + 192])));
                    #pragma unroll
                    for (int m2 = 1; m2 < 64; m2 <<= 1) s1 += __shfl_xor(s1, m2, 64);
                    if (lane == 0) sh1[u] = tanhf_(s1 + sb1[u]);
                }
            }
            __syncthreads();   // E: sh1 visible

            // est layers 2-3 (redundant per-thread) + state update: waves 0-3
            if (tid < 256) {
                float esc[4];
                #pragma unroll
                for (int g = 0; g < 4; g++) {
                    float h2[4];
                    #pragma unroll
                    for (int j = 0; j < 4; j++) {
                        float s2 = sb2[g * 4 + j];
                        #pragma unroll
                        for (int q = 0; q < 8; q++)
                            s2 = fmaf(sh1[g * 8 + q], sW2[g * 32 + j * 8 + q], s2);
                        h2[j] = tanhf_(s2);
                    }
                    float s3 = sb3[g];
                    #pragma unroll
                    for (int q = 0; q < 4; q++) s3 = fmaf(h2[q], sW3[g * 4 + q], s3);
                    esc[g] = sigmoidf_(s3);
                }
                float f  = gact[tid]       * esc[0];
                float ii = gact[256 + tid] * esc[1];
                float gg = gact[512 + tid] * esc[2];
                float o  = gact[768 + tid] * esc[3];
                c_reg = fmaf(f, c_reg, ii * gg);
                h_reg = o * tanhf_(c_reg);
                __half hi = __float2half_rn(h_reg);
                hxh[tid] = hi;
                hxl[tid] = __float2half_rn(h_reg - __half2float(hi));
                out[((size_t)t * BATCH + b) * H_DIM + tid] = h_reg;
            }
            __syncthreads();   // C: new hx visible to all waves
        }
    }

    if (tid < 256) {
        const size_t stacked = (size_t)T_STEPS * BATCH * H_DIM;
        out[stacked + (size_t)b * H_DIM + tid] = h_reg;
        out[stacked + (size_t)BATCH * H_DIM + (size_t)b * H_DIM + tid] = c_reg;
    }
}

extern "C" void kernel_launch(void* const* d_in, const int* in_sizes, int n_in,
                              void* d_out, int out_size, void* d_ws, size_t ws_size,
                              hipStream_t stream) {
    const float* x     = (const float*)d_in[0];
    const float* Wf    = (const float*)d_in[1];
    const float* bf    = (const float*)d_in[2];
    const float* Wi    = (const float*)d_in[3];
    const float* bi    = (const float*)d_in[4];
    const float* Wg    = (const float*)d_in[5];
    const float* bg    = (const float*)d_in[6];
    const float* Wo    = (const float*)d_in[7];
    const float* bo    = (const float*)d_in[8];
    const float* estW1 = (const float*)d_in[9];
    const float* estb1 = (const float*)d_in[10];
    const float* estW2 = (const float*)d_in[11];
    const float* estb2 = (const float*)d_in[12];
    const float* estW3 = (const float*)d_in[13];
    const float* estb3 = (const float*)d_in[14];

    uint4* WX4   = (uint4*)d_ws;                 // 32768 uint4 = 512 KB
    uint4* WH4   = WX4 + 32768;                  // 512 KB
    float* biasc = (float*)(WH4 + 32768);        // 4 KB

    prep_kernel<<<128, 256, 0, stream>>>(Wf, Wi, Wg, Wo, bf, bi, bg, bo,
                                         WX4, WH4, biasc);
    qlstm_kernel<<<BATCH, 512, 0, stream>>>(
        x, WX4, WH4, biasc,
        estW1, estb1, estW2, estb2, estW3, estb3, (float*)d_out);
}